// Round 12
// baseline (265.255 us; speedup 1.0000x reference)
//
#include <hip/hip_runtime.h>
#include <math.h>

// Problem constants (from reference setup_inputs)
#define BBATCH 16
#define NPTS   4096
#define MPTS   1024
#define C1c    128
#define C2c    256
#define CINc   384
#define H1c    256
#define H2c    128
#define TN     64

typedef _Float16 f16x8 __attribute__((ext_vector_type(8)));
typedef _Float16 f16x4 __attribute__((ext_vector_type(4)));
typedef float    f32x4 __attribute__((ext_vector_type(4)));

// Raw barrier: drain LDS ops only; global prefetch loads stay in flight.
#define BAR() do { asm volatile("s_waitcnt lgkmcnt(0)" ::: "memory"); \
                   __builtin_amdgcn_s_barrier(); } while (0)

// ---- LDS layout (bytes) ---------------------------------------------------
// RESIDENCY MATH (from measured bounds): usable LDS/CU in [139.3, 153.6) KB
//   (R16: 4 x 34816 resident at 78% occ; R14: 3 x 51200 did NOT fit).
//   => 3 blocks/CU needs LDS <= ~46.4 KB. This round: 45056 B -> 135.2 KB for
//   3 blocks, provably within the usable range. 24 waves/CU vs 16 before.
// union [0,32768):
//   phase A: inv dbuf 2 x [4 cc][4 nt][64 lane][8 f16] = 32768 B
//   phase B: s_X frags [8 kq][4 nt][64][8] f16 = 32768 B  (interp only; the p1
//            half of K is per-lane-gathered from global in phase B kc 0..3 —
//            32 KB tile, L1/L2-absorbed 8x redundancy)
//   phase C: s_H frags [8 oc][4 nt][64][8] f16 = 32768 B
// s_xyz2 [1024][3] f32 = 12288 B at 32768 (KEPT in LDS: R8 proved global-xyz2
//   blows gen live ranges; dead after ss=6 barrier)
// s_red 512 f32 OVERLAID at 32768 into dead xyz2 (first write is after ss=6's
//   barrier + ss=7's compute; xyz2's last read is gen(7) during ss=6)
// Total 45056 B.
//
// SESSION LESSONS BAKED IN (do not perturb):
//  - ~10 regs from the spill cliff: R8/R10/R16/R18 all spilled via structural
//    or even hint-removal codegen shifts. Phase A (gen_g, ring-4 loadA) and
//    the setprio fences are byte-identical to R14 (52 VGPR, no spill).
//  - s_setprio REQUIRED (R18: removal -> +12 VGPR + 8 MB spill + 4.3 us).
//  - __launch_bounds__(512,6): 85-reg cap = exactly the class 24 waves/CU
//    needs; demand ~52-70 leaves margin (R16 died forcing the 64-reg class).
#define INV_HALF   8192            // f16 elems per inv buffer (16384 B)
#define OFF_XYZ2   32768
#define OFF_RED    32768           // overlay into xyz2 (dead by then)
#define SMEM_BYTES 45056

// ---- fragment-swizzled workspace layout (f16 elements), unchanged ----
#define NFRAG_P2  (BBATCH * 32 * 16 * 64)        // 524288
#define NFRAG_W1  (16 * 12 * 64)                 // 12288
#define NFRAG_W2  (8 * 8 * 64)                   // 4096
#define WS_P2S  0
#define WS_W1S  (NFRAG_P2 * 8)                   // 4194304
#define WS_W2S  (WS_W1S + NFRAG_W1 * 8)
#define WS_F16_TOTAL (WS_W2S + NFRAG_W2 * 8)     // 4325376 f16 = 8650752 B

// ---------------------------------------------------------------------------
// pre-pass: convert + swizzle p2 / W1 / W2 into fragment-contiguous f16
__global__ __launch_bounds__(256) void cvt_swz(
    const float* __restrict__ p2, const float* __restrict__ W1,
    const float* __restrict__ W2, _Float16* __restrict__ ws)
{
    const int t = blockIdx.x * 256 + threadIdx.x;   // one fragment (8 f16) per thread
    const float* src;
    _Float16* dst;
    if (t < NFRAG_P2) {
        const int lane = t & 63, wt = (t >> 6) & 15, s = (t >> 10) & 31, b = t >> 15;
        const int c = wt * 16 + (lane & 15);
        const int m = s * 32 + (lane >> 4) * 8;
        src = p2 + ((size_t)(b * C2c + c)) * MPTS + m;
        dst = ws + WS_P2S + (size_t)t * 8;
    } else if (t < NFRAG_P2 + NFRAG_W1) {
        const int u = t - NFRAG_P2;
        const int lane = u & 63, kc = (u >> 6) % 12, wt = (u >> 6) / 12;
        const int o = wt * 16 + (lane & 15);
        const int k = kc * 32 + (lane >> 4) * 8;
        src = W1 + (size_t)o * CINc + k;
        dst = ws + WS_W1S + (size_t)u * 8;
    } else {
        const int v = t - NFRAG_P2 - NFRAG_W1;
        const int lane = v & 63, oc = (v >> 6) & 7, wt2 = v >> 9;
        const int o = wt2 * 16 + (lane & 15);
        const int k = oc * 32 + (lane >> 4) * 8;
        src = W2 + (size_t)o * H1c + k;
        dst = ws + WS_W2S + (size_t)v * 8;
    }
    const float4 a0 = *(const float4*)(src);
    const float4 a1 = *(const float4*)(src + 4);
    f16x8 h;
    h[0] = (_Float16)a0.x; h[1] = (_Float16)a0.y; h[2] = (_Float16)a0.z; h[3] = (_Float16)a0.w;
    h[4] = (_Float16)a1.x; h[5] = (_Float16)a1.y; h[6] = (_Float16)a1.z; h[7] = (_Float16)a1.w;
    *(f16x8*)dst = h;
}

// ---------------------------------------------------------------------------
// R20 = R14 with the block shrunk to 45056 B LDS for 3-blocks/CU residency
// (the one lever every flat round lacked). Changes vs R14, each derisked:
//  - p1 staging removed from phase A/s_X; phase B kc 0..3 gathers p1 per-lane
//    from global (R8/R16 mechanism; their failures were spill from OTHER edits).
//  - s_red overlaid into dead xyz2; interp writes kq = w into [0,32K).
//  - peel deleted (existed only for p1); loop reverts to R11's guarded shape.
//  - __launch_bounds__(512,6). Phase A internals byte-identical to R14.
template <bool F16P>
__global__ __launch_bounds__(512, 6) void fp_mfma17(
    const float* __restrict__ xyz1, const float* __restrict__ xyz2,
    const float* __restrict__ p1,   const float* __restrict__ p2,
    const float* __restrict__ W1,   const float* __restrict__ b1v,
    const float* __restrict__ W2,   const float* __restrict__ b2v,
    const _Float16* __restrict__ p2s, const _Float16* __restrict__ W1s,
    const _Float16* __restrict__ W2s,
    float* __restrict__ out)
{
    __shared__ __align__(16) char smem[SMEM_BYTES];
    _Float16* s_inv  = (_Float16*)smem;
    _Float16* s_X    = (_Float16*)smem;
    _Float16* s_H    = (_Float16*)smem;
    float*    s_xyz2 = (float*)(smem + OFF_XYZ2);
    float*    s_red  = (float*)(smem + OFF_RED);   // overlays dead xyz2

    const int tid  = threadIdx.x;
    const int w    = tid >> 6;    // wave 0..7
    const int L    = tid & 63;
    const int quad = L >> 4;
    const int l16  = L & 15;

    // XCD swizzle: each XCD sees 2 batches -> p2s working set (1 MB) L2-resident
    const int id = blockIdx.x;            // 1024 blocks
    const int b  = (id & 7) * 2 + ((id >> 3) & 1);
    const int n0 = (id >> 4) * TN;

    const float* __restrict__ z2b = xyz2 + (size_t)b * MPTS * 3;
    const float* __restrict__ p2b = p2   + (size_t)b * C2c * MPTS;
    const _Float16* __restrict__ p2sb =
        F16P ? (p2s + (((size_t)b * 32 * 16 + (size_t)w * 2) * 64 + L) * 8) : (const _Float16*)nullptr;

    // stage xyz2 (12 KB, coalesced f32x4)
    for (int i = tid; i < MPTS * 3 / 4; i += 512)
        ((f32x4*)s_xyz2)[i] = ((const f32x4*)z2b)[i];

    const float x1x = xyz1[((size_t)b * NPTS + n0 + L) * 3 + 0];
    const float x1y = xyz1[((size_t)b * NPTS + n0 + L) * 3 + 1];
    const float x1z = xyz1[((size_t)b * NPTS + n0 + L) * 3 + 2];

    f32x4 acc[2][4];   // [ct][nt]: row c = w*32+ct*16+quad*4+r, col n = nt*16+l16
    #pragma unroll
    for (int ct = 0; ct < 2; ++ct)
        #pragma unroll
        for (int nt = 0; nt < 4; ++nt)
            acc[ct][nt] = (f32x4){0.f, 0.f, 0.f, 0.f};

    float ssum = 0.f;
    f16x8 Aa[4][2];    // A-frag ring, slot = chunk & 3 (prefetch distance 2)

    auto loadA = [&](int s, f16x8 dst[2]) {
        if (F16P) {
            const _Float16* ap = p2sb + (size_t)s * (16 * 64 * 8);
            #pragma unroll
            for (int ct = 0; ct < 2; ++ct)
                dst[ct] = *(const f16x8*)(ap + (size_t)ct * (64 * 8));
        } else {
            const float* ap = p2b + (size_t)(w * 32 + l16) * MPTS + s * 32 + quad * 8;
            #pragma unroll
            for (int ct = 0; ct < 2; ++ct) {
                const float4 a0 = *(const float4*)(ap + (size_t)ct * (16 * MPTS));
                const float4 a1 = *(const float4*)(ap + (size_t)ct * (16 * MPTS) + 4);
                f16x8 h;
                h[0] = (_Float16)a0.x; h[1] = (_Float16)a0.y; h[2] = (_Float16)a0.z; h[3] = (_Float16)a0.w;
                h[4] = (_Float16)a1.x; h[5] = (_Float16)a1.y; h[6] = (_Float16)a1.z; h[7] = (_Float16)a1.w;
                dst[ct] = h;
            }
        }
    };

    // one 8-m group of super-chunk ss_ into frag buffer (ss_&1), g in {0,1}:
    // thread (w,L): n=L, m = ss_*128 + w*16 + g*8 + i
    //   -> frag (cc = w>>1, nt = quad), k-slot q' = (w&1)*2+g, lane l16.
    auto gen_g = [&](int ss_, int g) {
        _Float16* buf = s_inv + (ss_ & 1) * INV_HALF;
        const float* zp = s_xyz2 + (size_t)(ss_ * 128 + w * 16 + g * 8) * 3;
        f32x4 zr[6];
        #pragma unroll
        for (int j = 0; j < 6; ++j) zr[j] = ((const f32x4*)zp)[j];
        const float* zv = (const float*)zr;
        f16x8 iv;
        #pragma unroll
        for (int i = 0; i < 8; ++i) {
            const float dx = x1x - zv[3 * i + 0];
            const float dy = x1y - zv[3 * i + 1];
            const float dz = x1z - zv[3 * i + 2];
            const float d2 = fmaf(dx, dx, fmaf(dy, dy, fmaf(dz, dz, 1e-12f)));
            const float inv = __builtin_amdgcn_rsqf(d2);
            ssum += inv;
            iv[i] = (_Float16)inv;
        }
        *(f16x8*)(buf + ((((w >> 1) * 4 + quad) * 64) + ((w & 1) * 2 + g) * 16 + l16) * 8) = iv;
    };

    loadA(0, Aa[0]);
    loadA(1, Aa[1]);
    BAR();             // xyz2 staged (lgkm drain; A-prefetch stays in flight)
    gen_g(0, 0);
    gen_g(0, 1);
    BAR();             // super-chunk 0 visible

    // ---- phase A: ss = 0..7, guarded ring prefetch (R11 loop shape) ----
    for (int ss = 0; ss < 8; ++ss) {
        const _Float16* buf = s_inv + (ss & 1) * INV_HALF;
        #pragma unroll
        for (int cc = 0; cc < 4; ++cc) {
            const int s = ss * 4 + cc;
            if (s + 2 < 32) loadA(s + 2, Aa[(cc + 2) & 3]);   // distance-2 ring
            if (ss + 1 < 8 && cc < 2) gen_g(ss + 1, cc);      // inv VALU interleaved
            __builtin_amdgcn_s_setprio(1);
            #pragma unroll
            for (int nt = 0; nt < 4; ++nt) {
                const f16x8 bf = *(const f16x8*)(buf + ((cc * 4 + nt) * 64 + L) * 8);
                #pragma unroll
                for (int ct = 0; ct < 2; ++ct)
                    acc[ct][nt] = __builtin_amdgcn_mfma_f32_16x16x32_f16(Aa[cc][ct], bf, acc[ct][nt], 0, 0, 0);
            }
            __builtin_amdgcn_s_setprio(0);
        }
        BAR();   // reads of buf(ss) done; writes of buf(ss+1) done; vm loads live
    }

    // ---- S[n] reduction (s_red overlays xyz2: dead since ss=6's barrier) ----
    s_red[tid] = ssum;
    BAR();
    if (tid < 64) {
        float s = 0.f;
        #pragma unroll
        for (int wv = 0; wv < 8; ++wv) s += s_red[wv * 64 + tid];
        s_red[tid] = 1.0f / s;
    }
    BAR();   // recip ready; inv dbuf dead -> interp overlay safe

    // phase-B prefetch issued now: flies across the interp work + barrier
    f16x8 afP[2][2];
    auto loadW1 = [&](int kc, f16x8 dst[2]) {
        if (F16P) {
            const _Float16* wp = W1s + (((size_t)(w * 2) * 12 + kc) * 64 + L) * 8;
            #pragma unroll
            for (int ct = 0; ct < 2; ++ct)
                dst[ct] = *(const f16x8*)(wp + (size_t)ct * (12 * 64 * 8));
        } else {
            const float* wp = W1 + (size_t)(w * 32 + l16) * CINc + kc * 32 + quad * 8;
            #pragma unroll
            for (int ct = 0; ct < 2; ++ct) {
                const float4 a0 = *(const float4*)(wp + ct * (16 * CINc));
                const float4 a1 = *(const float4*)(wp + ct * (16 * CINc) + 4);
                f16x8 h;
                h[0] = (_Float16)a0.x; h[1] = (_Float16)a0.y; h[2] = (_Float16)a0.z; h[3] = (_Float16)a0.w;
                h[4] = (_Float16)a1.x; h[5] = (_Float16)a1.y; h[6] = (_Float16)a1.z; h[7] = (_Float16)a1.w;
                dst[ct] = h;
            }
        }
    };
    loadW1(0, afP[0]);

    // interp -> s_X frags kq = w at [0,32K) (overlaying dead inv dbuf).
    //   value (n = nt*16+l16, c = w*32+ct*16+quad*4+r):
    //   lane slot = (ct*2 + (quad>>1))*16 + l16, elem offset (quad&1)*4 + r.
    {
        float rn4[4];
        #pragma unroll
        for (int nt = 0; nt < 4; ++nt) rn4[nt] = s_red[nt * 16 + l16];
        #pragma unroll
        for (int ct = 0; ct < 2; ++ct) {
            const int lp = (ct * 2 + (quad >> 1)) * 16 + l16;
            const int jo = (quad & 1) * 4;
            #pragma unroll
            for (int nt = 0; nt < 4; ++nt) {
                const f32x4 v = acc[ct][nt];
                const float r = rn4[nt];
                f16x4 hv;
                hv[0] = (_Float16)(v[0] * r);
                hv[1] = (_Float16)(v[1] * r);
                hv[2] = (_Float16)(v[2] * r);
                hv[3] = (_Float16)(v[3] * r);
                *(f16x4*)(s_X + (((size_t)(w * 4 + nt)) * 64 + lp) * 8 + jo) = hv;
            }
        }
    }
    BAR();   // interp frags complete; W1 frag-0 still in flight

    // ---------------- Phase B: h = relu(W1 @ [p1; U] + b1), K=384 ----------
    // kc 0..3: B-frags per-lane-gathered from p1 (32-KB tile, L1/L2-absorbed);
    // kc 4..11: contiguous s_X frag reads.
    f32x4 hacc[2][4];
    #pragma unroll
    for (int ct = 0; ct < 2; ++ct)
        #pragma unroll
        for (int nt = 0; nt < 4; ++nt)
            hacc[ct][nt] = (f32x4){0.f, 0.f, 0.f, 0.f};

    const float* p1base = p1 + (size_t)b * C1c * NPTS + n0;
    #pragma unroll
    for (int kc = 0; kc < 12; ++kc) {
        if (kc + 1 < 12) loadW1(kc + 1, afP[(kc + 1) & 1]);
        __builtin_amdgcn_s_setprio(1);
        #pragma unroll
        for (int nt = 0; nt < 4; ++nt) {
            f16x8 bf;
            if (kc < 4) {
                const float* pp = p1base + (size_t)(kc * 32 + quad * 8) * NPTS + nt * 16 + l16;
                float t[8];
                #pragma unroll
                for (int j = 0; j < 8; ++j) t[j] = pp[(size_t)j * NPTS];
                #pragma unroll
                for (int j = 0; j < 8; ++j) bf[j] = (_Float16)t[j];
            } else {
                bf = *(const f16x8*)(s_X + (((size_t)((kc - 4) * 4 + nt)) * 64 + L) * 8);
            }
            #pragma unroll
            for (int ct = 0; ct < 2; ++ct)
                hacc[ct][nt] = __builtin_amdgcn_mfma_f32_16x16x32_f16(afP[kc & 1][ct], bf, hacc[ct][nt], 0, 0, 0);
        }
        __builtin_amdgcn_s_setprio(0);
    }

    BAR();   // all s_X reads done before overlaying s_H

    // phase-C prefetch issued now: flies across h-stage + barrier
    f16x8 afP2[2];
    auto loadW2 = [&](int oc, f16x8& dst) {
        if (F16P) {
            dst = *(const f16x8*)(W2s + (((size_t)(w * 8 + oc)) * 64 + L) * 8);
        } else {
            const float* wp = W2 + (size_t)(w * 16 + l16) * H1c + oc * 32 + quad * 8;
            const float4 a0 = *(const float4*)(wp);
            const float4 a1 = *(const float4*)(wp + 4);
            f16x8 h;
            h[0] = (_Float16)a0.x; h[1] = (_Float16)a0.y; h[2] = (_Float16)a0.z; h[3] = (_Float16)a0.w;
            h[4] = (_Float16)a1.x; h[5] = (_Float16)a1.y; h[6] = (_Float16)a1.z; h[7] = (_Float16)a1.w;
            dst = h;
        }
    };
    loadW2(0, afP2[0]);

    // bias + relu + stage h -> s_H frag layout (oq = w, same slot math as interp)
    {
        f32x4 bb[2];
        #pragma unroll
        for (int ct = 0; ct < 2; ++ct)
            bb[ct] = *(const f32x4*)(b1v + w * 32 + ct * 16 + quad * 4);
        #pragma unroll
        for (int ct = 0; ct < 2; ++ct) {
            const int lp = (ct * 2 + (quad >> 1)) * 16 + l16;
            const int jo = (quad & 1) * 4;
            #pragma unroll
            for (int nt = 0; nt < 4; ++nt) {
                const f32x4 v = hacc[ct][nt];
                f16x4 hv;
                hv[0] = (_Float16)fmaxf(v[0] + bb[ct][0], 0.f);
                hv[1] = (_Float16)fmaxf(v[1] + bb[ct][1], 0.f);
                hv[2] = (_Float16)fmaxf(v[2] + bb[ct][2], 0.f);
                hv[3] = (_Float16)fmaxf(v[3] + bb[ct][3], 0.f);
                *(f16x4*)(s_H + (((size_t)(w * 4 + nt)) * 64 + lp) * 8 + jo) = hv;
            }
        }
    }
    BAR();

    // ---------------- Phase C: out = relu(W2 @ h + b2), K=256 --------------
    f32x4 oacc[4];
    #pragma unroll
    for (int nt = 0; nt < 4; ++nt)
        oacc[nt] = (f32x4){0.f, 0.f, 0.f, 0.f};

    #pragma unroll
    for (int oc = 0; oc < 8; ++oc) {
        if (oc + 1 < 8) loadW2(oc + 1, afP2[(oc + 1) & 1]);
        __builtin_amdgcn_s_setprio(1);
        #pragma unroll
        for (int nt = 0; nt < 4; ++nt) {
            const f16x8 bf = *(const f16x8*)(s_H + (((size_t)(oc * 4 + nt)) * 64 + L) * 8);
            oacc[nt] = __builtin_amdgcn_mfma_f32_16x16x32_f16(afP2[oc & 1], bf, oacc[nt], 0, 0, 0);
        }
        __builtin_amdgcn_s_setprio(0);
    }

    // epilogue: bias + relu + store (o = w*16 + quad*4 + j)
    {
        const f32x4 bb2 = *(const f32x4*)(b2v + w * 16 + quad * 4);
        #pragma unroll
        for (int nt = 0; nt < 4; ++nt) {
            float* op = out + ((size_t)b * H2c + w * 16 + quad * 4) * NPTS
                            + n0 + nt * 16 + l16;
            #pragma unroll
            for (int j = 0; j < 4; ++j)
                op[(size_t)j * NPTS] = fmaxf(oacc[nt][j] + bb2[j], 0.f);
        }
    }
}

extern "C" void kernel_launch(void* const* d_in, const int* in_sizes, int n_in,
                              void* d_out, int out_size, void* d_ws, size_t ws_size,
                              hipStream_t stream) {
    (void)in_sizes; (void)n_in; (void)out_size;
    const float* xyz1 = (const float*)d_in[0];
    const float* xyz2 = (const float*)d_in[1];
    const float* p1   = (const float*)d_in[2];
    const float* p2   = (const float*)d_in[3];
    const float* W1   = (const float*)d_in[4];
    const float* b1   = (const float*)d_in[5];
    const float* W2   = (const float*)d_in[6];
    const float* b2   = (const float*)d_in[7];
    float* out = (float*)d_out;

    dim3 grid(BBATCH * (NPTS / TN));   // 1024 blocks @ 3 resident/CU
    dim3 block(512);
    if (ws_size >= (size_t)WS_F16_TOTAL * 2) {
        _Float16* ws = (_Float16*)d_ws;
        const int nswz = NFRAG_P2 + NFRAG_W1 + NFRAG_W2;   // 540672 = 2112 * 256
        cvt_swz<<<dim3(nswz / 256), dim3(256), 0, stream>>>(p2, W1, W2, ws);
        fp_mfma17<true><<<grid, block, 0, stream>>>(xyz1, xyz2, p1, p2, W1, b1, W2, b2,
                                                    ws + WS_P2S, ws + WS_W1S, ws + WS_W2S, out);
    } else {
        fp_mfma17<false><<<grid, block, 0, stream>>>(xyz1, xyz2, p1, p2, W1, b1, W2, b2,
                                                     nullptr, nullptr, nullptr, out);
    }
}